// Round 9
// baseline (394.079 us; speedup 1.0000x reference)
//
#include <hip/hip_runtime.h>
#include <math.h>

#define B_  4
#define L_  2048
#define H_  8
#define D_  64
#define U_  40
#define HD  (H_*D_)   // 512

// ws layout (bytes): pacc[1280*64 f32]@0, pl[1280 f32]@327680,
// vmean[2048 f32]@332800  (memset 0..340992), M[65536 f32]@344064,
// mtop[1280 i32]@606208.  Total 611,328 B (proven safe in r7/r8).
#define OFF_PACC  0
#define OFF_PL    327680
#define OFF_VMEAN 332800
#define ZERO_BYTES 340992
#define OFF_M     344064
#define OFF_MTOP  606208

// ---------------------------------------------------------------------------
// threefry2x32 (jax partitionable stream) — verified bit-exact round 4.
// ---------------------------------------------------------------------------
struct U2 { unsigned a, b; };

__host__ __device__ constexpr unsigned rotl32c(unsigned x, int r){
  return (x<<r)|(x>>(32-r));
}

__host__ __device__ constexpr U2 tf2x32(unsigned k0, unsigned k1,
                                        unsigned x0, unsigned x1)
{
  const unsigned k2 = k0 ^ k1 ^ 0x1BD11BDAu;
  const int rA[4] = {13,15,26,6};
  const int rB[4] = {17,29,16,24};
  x0 += k0; x1 += k1;
  for (int i=0;i<4;i++){ x0+=x1; x1=rotl32c(x1,rA[i]); x1^=x0; }
  x0 += k1; x1 += k2 + 1u;
  for (int i=0;i<4;i++){ x0+=x1; x1=rotl32c(x1,rB[i]); x1^=x0; }
  x0 += k2; x1 += k0 + 2u;
  for (int i=0;i<4;i++){ x0+=x1; x1=rotl32c(x1,rA[i]); x1^=x0; }
  x0 += k0; x1 += k1 + 3u;
  for (int i=0;i<4;i++){ x0+=x1; x1=rotl32c(x1,rB[i]); x1^=x0; }
  x0 += k1; x1 += k2 + 4u;
  for (int i=0;i<4;i++){ x0+=x1; x1=rotl32c(x1,rA[i]); x1^=x0; }
  x0 += k2; x1 += k0 + 5u;
  return U2{x0, x1};
}

// ---------------------------------------------------------------------------
// Kernel 1: M[b,h,l] = max_s(q.k_s) - sum_s(q.k_s)/2048 over 40 sampled keys.
// One wave per (bh,l); 8 sample-groups x 8 lanes, coalesced 256 B row reads;
// idx inline (threefry). 512 consecutive blocks per bh -> L2 slab locality.
// ---------------------------------------------------------------------------
__global__ __launch_bounds__(256) void m_kernel(const float* __restrict__ q,
                                                const float* __restrict__ k,
                                                float*       __restrict__ M)
{
  int g    = blockIdx.x;        // 16384
  int bh   = g >> 9;
  int lblk = g & 511;
  int w    = threadIdx.x >> 6, lane = threadIdx.x & 63;
  int l    = lblk*4 + w;
  int b = bh >> 3, h = bh & 7;
  int grp  = lane >> 3;
  int l8   = lane & 7;
  const float* qrow = q + (size_t)(b*L_ + l)*HD + h*D_;
  float4 q0 = *(const float4*)(qrow + l8*8);
  float4 q1 = *(const float4*)(qrow + l8*8 + 4);
  constexpr U2 K2 = tf2x32(0u, 42u, 0u, 1u);
  int myidx = 0;
  if (lane < U_){
    U2 r = tf2x32(K2.a, K2.b, 0u, (unsigned)(l*U_ + lane));
    myidx = (int)((r.a ^ r.b) & 2047u);
  }
  const float* kbase = k + (size_t)b*L_*HD + h*D_;
  float vmax = -INFINITY, vsum = 0.f;
  #pragma unroll
  for (int t=0;t<5;t++){
    int s = t*8 + grp;
    int kidx = __shfl(myidx, s, 64);
    const float* krow = kbase + (size_t)kidx*HD;
    float4 k0 = *(const float4*)(krow + l8*8);
    float4 k1 = *(const float4*)(krow + l8*8 + 4);
    float p = q0.x*k0.x + q0.y*k0.y + q0.z*k0.z + q0.w*k0.w
            + q1.x*k1.x + q1.y*k1.y + q1.z*k1.z + q1.w*k1.w;
    p += __shfl_xor(p, 1, 64);
    p += __shfl_xor(p, 2, 64);
    p += __shfl_xor(p, 4, 64);
    vmax = fmaxf(vmax, p);
    vsum += p;
  }
  vmax = fmaxf(vmax, __shfl_xor(vmax, 8, 64));
  vmax = fmaxf(vmax, __shfl_xor(vmax,16, 64));
  vmax = fmaxf(vmax, __shfl_xor(vmax,32, 64));
  vsum += __shfl_xor(vsum, 8, 64);
  vsum += __shfl_xor(vsum,16, 64);
  vsum += __shfl_xor(vsum,32, 64);
  if (lane == 0) M[bh*L_ + l] = vmax - vsum * (1.0f/(float)L_);
}

// ---------------------------------------------------------------------------
// Kernel 2: top-40 per (b,h). Per-thread running (max,idx) in registers;
// only the winner thread rescans its 8 slots each iteration.
// ---------------------------------------------------------------------------
__global__ __launch_bounds__(256) void topk_kernel(const float* __restrict__ M,
                                                   int* __restrict__ mtop)
{
  __shared__ float mv[L_];
  __shared__ float bv[4];
  __shared__ int   bix[4];
  __shared__ int   wsh;
  int bh = blockIdx.x;
  int tid = threadIdx.x, w = tid >> 6, lane = tid & 63;
  float tb = -INFINITY; int ti = tid;
  #pragma unroll
  for (int i=0;i<8;i++){
    float vv = M[bh*L_ + tid + 256*i];
    mv[tid + 256*i] = vv;
    if (vv > tb){ tb = vv; ti = tid + 256*i; }
  }
  for (int it=0; it<U_; ++it){
    float best = tb; int bi = ti;
    #pragma unroll
    for (int off=32; off; off>>=1){
      float ov = __shfl_xor(best, off, 64);
      int   oi = __shfl_xor(bi,   off, 64);
      if (ov > best || (ov == best && oi < bi)){ best = ov; bi = oi; }
    }
    if (lane == 0){ bv[w] = best; bix[w] = bi; }
    __syncthreads();
    if (tid == 0){
      float bb = bv[0]; int ii = bix[0];
      #pragma unroll
      for (int j=1;j<4;j++)
        if (bv[j] > bb || (bv[j] == bb && bix[j] < ii)){ bb = bv[j]; ii = bix[j]; }
      mtop[bh*U_ + it] = ii; wsh = ii;
    }
    __syncthreads();
    int wi = wsh;
    if (ti == wi){
      mv[wi] = -INFINITY;
      tb = -INFINITY; ti = tid;
      #pragma unroll
      for (int i=0;i<8;i++){
        float vv = mv[tid + 256*i];
        if (vv > tb){ tb = vv; ti = tid + 256*i; }
      }
    }
  }
}

// ---------------------------------------------------------------------------
// Kernel 3: V column sums (for mean), atomics into vmean (pre-zeroed).
// ---------------------------------------------------------------------------
__global__ __launch_bounds__(256) void vmean_kernel(const float* __restrict__ v,
                                                    float* __restrict__ vmean)
{
  int g = blockIdx.x;
  int bh = g & 31, chunk = g >> 5;
  int b = bh >> 3, h = bh & 7;
  int w = threadIdx.x >> 6, lane = threadIdx.x & 63;
  int l0 = chunk*128 + w*32;
  float s = 0.f;
  for (int i=0;i<32;i++)
    s += v[(size_t)(b*L_ + l0 + i)*HD + h*D_ + lane];
  atomicAdd(&vmean[bh*D_ + lane], s);
}

// ---------------------------------------------------------------------------
// Kernel 4: out[b][l][h][:] = V_mean (sum * 1/2048), float4 stores.
// ---------------------------------------------------------------------------
__global__ __launch_bounds__(256) void init_kernel(const float* __restrict__ vmean,
                                                   float* __restrict__ out)
{
  int i = blockIdx.x*256 + threadIdx.x;
  int d4 = i & 15;
  int h  = (i >> 4) & 7;
  int bl = i >> 7;
  int b  = bl >> 11;
  float4 vm = ((const float4*)(vmean + (b*H_ + h)*D_))[d4];
  const float sc = 1.0f/(float)L_;
  float4 o; o.x = vm.x*sc; o.y = vm.y*sc; o.z = vm.z*sc; o.w = vm.w*sc;
  ((float4*)out)[i] = o;
}

// ---------------------------------------------------------------------------
// Kernel 5: attention partials, one 128-key tile per block (512 blocks).
// ANTI-SPILL (r7/r8 hit VGPR=256 + 127 MB scratch; r6's loop shape gave 132):
//   (a) body wrapped in runtime-trip-count nt loop (nt=1) — pins r6's shape,
//   (b) __launch_bounds__(256,3): min 3 waves/EU -> hard cap ~170 VGPR,
//   (c) V never staged: PV reads V direct from global (lane=dim, coalesced
//       256 B/key, L1-served across waves) -> LDS 45 KB, 3 blocks/CU cap.
// scores: wave w owns queries w*10..+9, lane owns keys {lane, lane+64}.
// p = exp(s/8) (no max-shift; s~N(0,1), fp32-safe — validated r7/r8).
// Merge across kc via atomicAdd into pre-zeroed pacc/pl (611 KB ws).
// ---------------------------------------------------------------------------
__global__ __launch_bounds__(256, 3) void attn_kernel(const float* __restrict__ q,
                                                      const float* __restrict__ k,
                                                      const float* __restrict__ v,
                                                      const int*   __restrict__ mtop,
                                                      float* __restrict__ pacc,
                                                      float* __restrict__ pl,
                                                      int nt)
{
  __shared__ float sh[128*68 + 40*64];   // Kt (psQ overlays) + Qs = 45,056 B
  float* Kt  = sh;
  float* Qs  = sh + 128*68;
  float* psQ = sh;

  int g  = blockIdx.x;             // 512
  int bh = g & 31, kc = g >> 5;
  int b = bh >> 3, h = bh & 7;
  int tid = threadIdx.x, w = tid >> 6, lane = tid & 63;

  // stage Q (40 x 64 via mtop) once
  #pragma unroll
  for (int c=0;c<3;c++){
    int flat = c*256 + tid;
    int row = flat >> 4, col = flat & 15;
    if (row < U_){
      int lstar = mtop[bh*U_ + row];
      ((float4*)(Qs + row*64))[col] =
        ((const float4*)(q + (size_t)(b*L_ + lstar)*HD + h*D_))[col];
    }
  }

  float acc[10];
  #pragma unroll
  for (int qq=0;qq<10;qq++) acc[qq] = 0.f;

  for (int tt=0; tt<nt; ++tt){     // nt==1 at runtime; loop pins code shape
    int kt = (kc*nt + tt)*128;
    __syncthreads();
    #pragma unroll
    for (int c=0;c<8;c++){
      int flat = c*256 + tid;
      int row = flat >> 4, col = flat & 15;
      ((float4*)(Kt + row*68))[col] =
        ((const float4*)(k + (size_t)(b*L_ + kt + row)*HD + h*D_))[col];
    }
    __syncthreads();

    // scores: 10 queries x 2 keys per lane
    float s0[10], s1[10];
    #pragma unroll
    for (int qq=0;qq<10;qq++){ s0[qq] = 0.f; s1[qq] = 0.f; }
    const float* kr0 = Kt + lane*68;
    const float* kr1 = Kt + (lane+64)*68;
    #pragma unroll
    for (int t=0;t<16;t++){
      float4 k0 = ((const float4*)kr0)[t];
      float4 k1 = ((const float4*)kr1)[t];
      #pragma unroll
      for (int qq=0;qq<10;qq++){
        float4 qf = ((const float4*)(Qs + (w*10+qq)*64))[t];
        s0[qq] += k0.x*qf.x + k0.y*qf.y + k0.z*qf.z + k0.w*qf.w;
        s1[qq] += k1.x*qf.x + k1.y*qf.y + k1.z*qf.z + k1.w*qf.w;
      }
    }
    __syncthreads();   // Kt reads done before psQ overlay

    #pragma unroll
    for (int qq=0;qq<10;qq++){
      float p0 = __expf(s0[qq]*0.125f);
      float p1 = __expf(s1[qq]*0.125f);
      psQ[(w*10+qq)*128 + lane]      = p0;
      psQ[(w*10+qq)*128 + lane + 64] = p1;
      float ps = p0 + p1;
      #pragma unroll
      for (int off=32; off; off>>=1) ps += __shfl_xor(ps, off, 64);
      if (lane == 0) atomicAdd(&pl[bh*U_ + w*10 + qq], ps);
    }
    __syncthreads();   // psQ visible to all waves

    // PV: lane = output dim; V rows direct from global (coalesced), keys 0..127
    const float* vbase = v + (size_t)(b*L_ + kt)*HD + h*D_ + lane;
    for (int k4=0;k4<32;k4++){
      float v0 = vbase[(4*k4+0)*HD];
      float v1 = vbase[(4*k4+1)*HD];
      float v2 = vbase[(4*k4+2)*HD];
      float v3 = vbase[(4*k4+3)*HD];
      #pragma unroll
      for (int qq=0;qq<10;qq++){
        float4 pp = ((const float4*)(psQ + (w*10+qq)*128))[k4];
        acc[qq] += pp.x*v0 + pp.y*v1 + pp.z*v2 + pp.w*v3;
      }
    }
  }

  #pragma unroll
  for (int qq=0;qq<10;qq++)
    atomicAdd(&pacc[(size_t)(bh*U_ + w*10 + qq)*64 + lane], acc[qq]);
}

// ---------------------------------------------------------------------------
// Kernel 6: normalize and scatter the 40 selected rows per (b,h).
// ---------------------------------------------------------------------------
__global__ __launch_bounds__(256) void combine_kernel(const int* __restrict__ mtop,
                                                      const float* __restrict__ pacc,
                                                      const float* __restrict__ pl,
                                                      float* __restrict__ out)
{
  int gu = blockIdx.x*4 + (threadIdx.x >> 6);  // 0..1279
  int lane = threadIdx.x & 63;
  int bh = gu / U_, u = gu - bh*U_;
  int b = bh >> 3, h = bh & 7;
  int lstar = mtop[bh*U_ + u];
  out[(size_t)(b*L_ + lstar)*HD + h*D_ + lane] =
      pacc[(size_t)gu*64 + lane] / pl[gu];
}

// ---------------------------------------------------------------------------
extern "C" void kernel_launch(void* const* d_in, const int* in_sizes, int n_in,
                              void* d_out, int out_size, void* d_ws, size_t ws_size,
                              hipStream_t stream)
{
  const float* q = (const float*)d_in[0];
  const float* k = (const float*)d_in[1];
  const float* v = (const float*)d_in[2];
  float* out = (float*)d_out;

  float* pacc  = (float*)((char*)d_ws + OFF_PACC);
  float* pl    = (float*)((char*)d_ws + OFF_PL);
  float* vmean = (float*)((char*)d_ws + OFF_VMEAN);
  float* M     = (float*)((char*)d_ws + OFF_M);
  int*   mtop  = (int*)  ((char*)d_ws + OFF_MTOP);

  hipMemsetAsync(d_ws, 0, ZERO_BYTES, stream);   // pacc + pl + vmean
  m_kernel      <<<16384, 256, 0, stream>>>(q, k, M);
  topk_kernel   <<<32,    256, 0, stream>>>(M, mtop);
  vmean_kernel  <<<512,   256, 0, stream>>>(v, vmean);
  init_kernel   <<<4096,  256, 0, stream>>>(vmean, out);
  attn_kernel   <<<512,   256, 0, stream>>>(q, k, v, mtop, pacc, pl, 1);
  combine_kernel<<<320,   256, 0, stream>>>(mtop, pacc, pl, out);
}

// Round 10
// 218.643 us; speedup vs baseline: 1.8024x; 1.8024x over previous
//
#include <hip/hip_runtime.h>
#include <math.h>

#define B_  4
#define L_  2048
#define H_  8
#define D_  64
#define U_  40
#define HD  (H_*D_)   // 512

// ws layout (bytes) — stored partials, NO atomics (r9: 1.3M memory-side
// atomics => 300+ MB of TCC line traffic, attn was pure-BW-bound on it):
//   pacc4[1280*4*64 f32] @ 0          (1,310,720 B; (gu,kc) exclusive/block)
//   pl4  [1280*4 f32]    @ 1310720    (20,480 B)
//   vmean[2048 f32]      @ 1331200    (8,192 B; only this gets memset)
//   M    [65536 f32]     @ 1339392
//   mtop [1280 i32]      @ 1601536    -> total 1,606,656 B (< r5-proven 1.95 MB)
#define OFF_PACC  0
#define OFF_PL    1310720
#define OFF_VMEAN 1331200
#define OFF_M     1339392
#define OFF_MTOP  1601536

// ---------------------------------------------------------------------------
// threefry2x32 (jax partitionable stream) — verified bit-exact round 4.
// ---------------------------------------------------------------------------
struct U2 { unsigned a, b; };

__host__ __device__ constexpr unsigned rotl32c(unsigned x, int r){
  return (x<<r)|(x>>(32-r));
}

__host__ __device__ constexpr U2 tf2x32(unsigned k0, unsigned k1,
                                        unsigned x0, unsigned x1)
{
  const unsigned k2 = k0 ^ k1 ^ 0x1BD11BDAu;
  const int rA[4] = {13,15,26,6};
  const int rB[4] = {17,29,16,24};
  x0 += k0; x1 += k1;
  for (int i=0;i<4;i++){ x0+=x1; x1=rotl32c(x1,rA[i]); x1^=x0; }
  x0 += k1; x1 += k2 + 1u;
  for (int i=0;i<4;i++){ x0+=x1; x1=rotl32c(x1,rB[i]); x1^=x0; }
  x0 += k2; x1 += k0 + 2u;
  for (int i=0;i<4;i++){ x0+=x1; x1=rotl32c(x1,rA[i]); x1^=x0; }
  x0 += k0; x1 += k1 + 3u;
  for (int i=0;i<4;i++){ x0+=x1; x1=rotl32c(x1,rB[i]); x1^=x0; }
  x0 += k1; x1 += k2 + 4u;
  for (int i=0;i<4;i++){ x0+=x1; x1=rotl32c(x1,rA[i]); x1^=x0; }
  x0 += k2; x1 += k0 + 5u;
  return U2{x0, x1};
}

// ---------------------------------------------------------------------------
// Kernel 1: M[b,h,l] = max_s(q.k_s) - sum_s(q.k_s)/2048 over 40 sampled keys.
// One wave per (bh,l); 8 sample-groups x 8 lanes, coalesced 256 B row reads;
// idx inline (threefry). 512 consecutive blocks per bh -> L2 slab locality.
// ---------------------------------------------------------------------------
__global__ __launch_bounds__(256) void m_kernel(const float* __restrict__ q,
                                                const float* __restrict__ k,
                                                float*       __restrict__ M)
{
  int g    = blockIdx.x;        // 16384
  int bh   = g >> 9;
  int lblk = g & 511;
  int w    = threadIdx.x >> 6, lane = threadIdx.x & 63;
  int l    = lblk*4 + w;
  int b = bh >> 3, h = bh & 7;
  int grp  = lane >> 3;
  int l8   = lane & 7;
  const float* qrow = q + (size_t)(b*L_ + l)*HD + h*D_;
  float4 q0 = *(const float4*)(qrow + l8*8);
  float4 q1 = *(const float4*)(qrow + l8*8 + 4);
  constexpr U2 K2 = tf2x32(0u, 42u, 0u, 1u);
  int myidx = 0;
  if (lane < U_){
    U2 r = tf2x32(K2.a, K2.b, 0u, (unsigned)(l*U_ + lane));
    myidx = (int)((r.a ^ r.b) & 2047u);
  }
  const float* kbase = k + (size_t)b*L_*HD + h*D_;
  float vmax = -INFINITY, vsum = 0.f;
  #pragma unroll
  for (int t=0;t<5;t++){
    int s = t*8 + grp;
    int kidx = __shfl(myidx, s, 64);
    const float* krow = kbase + (size_t)kidx*HD;
    float4 k0 = *(const float4*)(krow + l8*8);
    float4 k1 = *(const float4*)(krow + l8*8 + 4);
    float p = q0.x*k0.x + q0.y*k0.y + q0.z*k0.z + q0.w*k0.w
            + q1.x*k1.x + q1.y*k1.y + q1.z*k1.z + q1.w*k1.w;
    p += __shfl_xor(p, 1, 64);
    p += __shfl_xor(p, 2, 64);
    p += __shfl_xor(p, 4, 64);
    vmax = fmaxf(vmax, p);
    vsum += p;
  }
  vmax = fmaxf(vmax, __shfl_xor(vmax, 8, 64));
  vmax = fmaxf(vmax, __shfl_xor(vmax,16, 64));
  vmax = fmaxf(vmax, __shfl_xor(vmax,32, 64));
  vsum += __shfl_xor(vsum, 8, 64);
  vsum += __shfl_xor(vsum,16, 64);
  vsum += __shfl_xor(vsum,32, 64);
  if (lane == 0) M[bh*L_ + l] = vmax - vsum * (1.0f/(float)L_);
}

// ---------------------------------------------------------------------------
// Kernel 2: top-40 per (b,h). Per-thread running (max,idx) in registers;
// only the winner thread rescans its 8 slots each iteration.
// ---------------------------------------------------------------------------
__global__ __launch_bounds__(256) void topk_kernel(const float* __restrict__ M,
                                                   int* __restrict__ mtop)
{
  __shared__ float mv[L_];
  __shared__ float bv[4];
  __shared__ int   bix[4];
  __shared__ int   wsh;
  int bh = blockIdx.x;
  int tid = threadIdx.x, w = tid >> 6, lane = tid & 63;
  float tb = -INFINITY; int ti = tid;
  #pragma unroll
  for (int i=0;i<8;i++){
    float vv = M[bh*L_ + tid + 256*i];
    mv[tid + 256*i] = vv;
    if (vv > tb){ tb = vv; ti = tid + 256*i; }
  }
  for (int it=0; it<U_; ++it){
    float best = tb; int bi = ti;
    #pragma unroll
    for (int off=32; off; off>>=1){
      float ov = __shfl_xor(best, off, 64);
      int   oi = __shfl_xor(bi,   off, 64);
      if (ov > best || (ov == best && oi < bi)){ best = ov; bi = oi; }
    }
    if (lane == 0){ bv[w] = best; bix[w] = bi; }
    __syncthreads();
    if (tid == 0){
      float bb = bv[0]; int ii = bix[0];
      #pragma unroll
      for (int j=1;j<4;j++)
        if (bv[j] > bb || (bv[j] == bb && bix[j] < ii)){ bb = bv[j]; ii = bix[j]; }
      mtop[bh*U_ + it] = ii; wsh = ii;
    }
    __syncthreads();
    int wi = wsh;
    if (ti == wi){
      mv[wi] = -INFINITY;
      tb = -INFINITY; ti = tid;
      #pragma unroll
      for (int i=0;i<8;i++){
        float vv = mv[tid + 256*i];
        if (vv > tb){ tb = vv; ti = tid + 256*i; }
      }
    }
  }
}

// ---------------------------------------------------------------------------
// Kernel 3: V column sums (for mean), atomics into vmean (pre-zeroed).
// (2048 destinations only — not the pathological case.)
// ---------------------------------------------------------------------------
__global__ __launch_bounds__(256) void vmean_kernel(const float* __restrict__ v,
                                                    float* __restrict__ vmean)
{
  int g = blockIdx.x;
  int bh = g & 31, chunk = g >> 5;
  int b = bh >> 3, h = bh & 7;
  int w = threadIdx.x >> 6, lane = threadIdx.x & 63;
  int l0 = chunk*128 + w*32;
  float s = 0.f;
  for (int i=0;i<32;i++)
    s += v[(size_t)(b*L_ + l0 + i)*HD + h*D_ + lane];
  atomicAdd(&vmean[bh*D_ + lane], s);
}

// ---------------------------------------------------------------------------
// Kernel 4: out[b][l][h][:] = V_mean (sum * 1/2048), float4 stores.
// ---------------------------------------------------------------------------
__global__ __launch_bounds__(256) void init_kernel(const float* __restrict__ vmean,
                                                   float* __restrict__ out)
{
  int i = blockIdx.x*256 + threadIdx.x;
  int d4 = i & 15;
  int h  = (i >> 4) & 7;
  int bl = i >> 7;
  int b  = bl >> 11;
  float4 vm = ((const float4*)(vmean + (b*H_ + h)*D_))[d4];
  const float sc = 1.0f/(float)L_;
  float4 o; o.x = vm.x*sc; o.y = vm.y*sc; o.z = vm.z*sc; o.w = vm.w*sc;
  ((float4*)out)[i] = o;
}

// ---------------------------------------------------------------------------
// Kernel 5: attention partials, STORED (no atomics — r9 lesson). Grid = 256:
// bh = g&31, j = g>>5: kc = j&3 (512-key chunk), qg = j>>2 (20-query half).
// All 8 blocks of a bh share one XCD (g%8 = bh%8) -> per-XCD K+V = 4 MB = L2.
// Block: 4 waves; wave owns 5 queries; nt=4 runtime-trip tiles of 128 keys
// (runtime loop + __launch_bounds__(256,3) = r9-proven anti-spill, VGPR 84).
// Kt pad-68 (0 conflicts measured), Vt in LDS (r8-proven), psQ overlays Kt.
// p = exp(s/8), no max-shift (r7/r8-validated). Partials written to the
// block's exclusive (gu,kc) slice: zero atomic traffic.
// ---------------------------------------------------------------------------
__global__ __launch_bounds__(256, 3) void attn_kernel(const float* __restrict__ q,
                                                      const float* __restrict__ k,
                                                      const float* __restrict__ v,
                                                      const int*   __restrict__ mtop,
                                                      float* __restrict__ pacc,
                                                      float* __restrict__ pl,
                                                      int nt)
{
  __shared__ float sh[128*68 + 128*64 + 20*64];  // Kt + Vt + Qs = 72,704 B
  float* Kt  = sh;                 // psQ[20][128] overlays after scores
  float* Vt  = sh + 128*68;
  float* Qs  = sh + 128*68 + 128*64;
  float* psQ = sh;

  int g  = blockIdx.x;             // 256
  int bh = g & 31, j = g >> 5;
  int kc = j & 3,  qg = j >> 2;
  int b = bh >> 3, h = bh & 7;
  int tid = threadIdx.x, w = tid >> 6, lane = tid & 63;

  // stage Qs: 20 rows x 16 float4 = 320 float4
  #pragma unroll
  for (int c=0;c<2;c++){
    int flat = c*256 + tid;
    if (flat < 320){
      int row = flat >> 4, col = flat & 15;
      int lstar = mtop[bh*U_ + qg*20 + row];
      ((float4*)(Qs + row*64))[col] =
        ((const float4*)(q + (size_t)(b*L_ + lstar)*HD + h*D_))[col];
    }
  }

  float acc[5], lsum[5];
  #pragma unroll
  for (int qq=0;qq<5;qq++){ acc[qq] = 0.f; lsum[qq] = 0.f; }

  for (int tt=0; tt<nt; ++tt){     // nt==4 runtime; loop pins code shape
    int kt = (kc*nt + tt)*128;
    __syncthreads();               // Qs ready / prior tile's psQ+Vt reads done
    #pragma unroll
    for (int c=0;c<8;c++){
      int flat = c*256 + tid;
      int row = flat >> 4, col = flat & 15;
      ((float4*)(Kt + row*68))[col] =
        ((const float4*)(k + (size_t)(b*L_ + kt + row)*HD + h*D_))[col];
      ((float4*)(Vt + row*64))[col] =
        ((const float4*)(v + (size_t)(b*L_ + kt + row)*HD + h*D_))[col];
    }
    __syncthreads();

    // scores: 5 queries x 2 keys per lane
    float s0[5], s1[5];
    #pragma unroll
    for (int qq=0;qq<5;qq++){ s0[qq] = 0.f; s1[qq] = 0.f; }
    const float* kr0 = Kt + lane*68;
    const float* kr1 = Kt + (lane+64)*68;
    #pragma unroll
    for (int t=0;t<16;t++){
      float4 k0 = ((const float4*)kr0)[t];
      float4 k1 = ((const float4*)kr1)[t];
      #pragma unroll
      for (int qq=0;qq<5;qq++){
        float4 qf = ((const float4*)(Qs + (w*5+qq)*64))[t];
        s0[qq] += k0.x*qf.x + k0.y*qf.y + k0.z*qf.z + k0.w*qf.w;
        s1[qq] += k1.x*qf.x + k1.y*qf.y + k1.z*qf.z + k1.w*qf.w;
      }
    }
    __syncthreads();   // Kt reads done before psQ overlay

    #pragma unroll
    for (int qq=0;qq<5;qq++){
      float p0 = __expf(s0[qq]*0.125f);
      float p1 = __expf(s1[qq]*0.125f);
      psQ[(w*5+qq)*128 + lane]      = p0;
      psQ[(w*5+qq)*128 + lane + 64] = p1;
      lsum[qq] += p0 + p1;         // per-lane; reduced once in epilogue
    }
    __syncthreads();   // psQ visible to all waves (PV reads own-wave only,
                       // but Kt restage next iter needs all waves done)

    // PV: lane = output dim; wave's 5 queries, all 128 keys from Vt
    for (int k4=0;k4<32;k4++){
      float v0 = Vt[(4*k4+0)*64 + lane];
      float v1 = Vt[(4*k4+1)*64 + lane];
      float v2 = Vt[(4*k4+2)*64 + lane];
      float v3 = Vt[(4*k4+3)*64 + lane];
      #pragma unroll
      for (int qq=0;qq<5;qq++){
        float4 pp = ((const float4*)(psQ + (w*5+qq)*128))[k4];
        acc[qq] += pp.x*v0 + pp.y*v1 + pp.z*v2 + pp.w*v3;
      }
    }
  }

  // epilogue: exclusive (gu,kc) partial slice — no atomics
  #pragma unroll
  for (int qq=0;qq<5;qq++){
    float ls = lsum[qq];
    #pragma unroll
    for (int off=32; off; off>>=1) ls += __shfl_xor(ls, off, 64);
    int gu = bh*U_ + qg*20 + w*5 + qq;
    pacc[(size_t)(gu*4 + kc)*64 + lane] = acc[qq];
    if (lane == 0) pl[gu*4 + kc] = ls;
  }
}

// ---------------------------------------------------------------------------
// Kernel 6: sum 4 kc partials per (bh,u), normalize, scatter selected rows.
// ---------------------------------------------------------------------------
__global__ __launch_bounds__(256) void combine_kernel(const int* __restrict__ mtop,
                                                      const float* __restrict__ pacc,
                                                      const float* __restrict__ pl,
                                                      float* __restrict__ out)
{
  int gu = blockIdx.x*4 + (threadIdx.x >> 6);  // 0..1279
  int lane = threadIdx.x & 63;
  int bh = gu / U_, u = gu - bh*U_;
  float a = 0.f, L = 0.f;
  #pragma unroll
  for (int c=0;c<4;c++){
    a += pacc[(size_t)(gu*4 + c)*64 + lane];
    L += pl[gu*4 + c];
  }
  int b = bh >> 3, h = bh & 7;
  int lstar = mtop[bh*U_ + u];
  out[(size_t)(b*L_ + lstar)*HD + h*D_ + lane] = a / L;
}

// ---------------------------------------------------------------------------
extern "C" void kernel_launch(void* const* d_in, const int* in_sizes, int n_in,
                              void* d_out, int out_size, void* d_ws, size_t ws_size,
                              hipStream_t stream)
{
  const float* q = (const float*)d_in[0];
  const float* k = (const float*)d_in[1];
  const float* v = (const float*)d_in[2];
  float* out = (float*)d_out;

  float* pacc  = (float*)((char*)d_ws + OFF_PACC);
  float* pl    = (float*)((char*)d_ws + OFF_PL);
  float* vmean = (float*)((char*)d_ws + OFF_VMEAN);
  float* M     = (float*)((char*)d_ws + OFF_M);
  int*   mtop  = (int*)  ((char*)d_ws + OFF_MTOP);

  hipMemsetAsync(vmean, 0, 2048*sizeof(float), stream);
  m_kernel      <<<16384, 256, 0, stream>>>(q, k, M);
  topk_kernel   <<<32,    256, 0, stream>>>(M, mtop);
  vmean_kernel  <<<512,   256, 0, stream>>>(v, vmean);
  init_kernel   <<<4096,  256, 0, stream>>>(vmean, out);
  attn_kernel   <<<256,   256, 0, stream>>>(q, k, v, mtop, pacc, pl, 4);
  combine_kernel<<<320,   256, 0, stream>>>(mtop, pacc, pl, out);
}

// Round 11
// 211.040 us; speedup vs baseline: 1.8673x; 1.0360x over previous
//
#include <hip/hip_runtime.h>
#include <math.h>

#define B_  4
#define L_  2048
#define H_  8
#define D_  64
#define U_  40
#define HD  (H_*D_)   // 512

// ---------------------------------------------------------------------------
// Workspace: runtime-selected layout.
//  KC=8 (needs 3,265,536 B): pacc[1280*8*64]@0, pl[1280*8]@2621440,
//    vmean@2662400, M@2670592, mtop@2932736, idx@2937856 -> 3,265,536 total
//  KC=4 (needs 1,934,336 B; r5/r10-proven): pacc[1280*4*64]@0, pl@1310720,
//    vmean@1331200, M@1339392, mtop@1601536, idx@1606656 -> 1,934,336 total
// ---------------------------------------------------------------------------
#define WS_NEED_KC8 3265536

// ---------------------------------------------------------------------------
// threefry2x32 (jax partitionable stream) — verified bit-exact round 4.
// randint(key(42),(2048,40),0,2048) = tf(k2,(0,j)).b1 ^ .b2 & 2047,
// k2 = tf((0,42),(0,1)) constexpr.
// ---------------------------------------------------------------------------
struct U2 { unsigned a, b; };

__host__ __device__ constexpr unsigned rotl32c(unsigned x, int r){
  return (x<<r)|(x>>(32-r));
}

__host__ __device__ constexpr U2 tf2x32(unsigned k0, unsigned k1,
                                        unsigned x0, unsigned x1)
{
  const unsigned k2 = k0 ^ k1 ^ 0x1BD11BDAu;
  const int rA[4] = {13,15,26,6};
  const int rB[4] = {17,29,16,24};
  x0 += k0; x1 += k1;
  for (int i=0;i<4;i++){ x0+=x1; x1=rotl32c(x1,rA[i]); x1^=x0; }
  x0 += k1; x1 += k2 + 1u;
  for (int i=0;i<4;i++){ x0+=x1; x1=rotl32c(x1,rB[i]); x1^=x0; }
  x0 += k2; x1 += k0 + 2u;
  for (int i=0;i<4;i++){ x0+=x1; x1=rotl32c(x1,rA[i]); x1^=x0; }
  x0 += k0; x1 += k1 + 3u;
  for (int i=0;i<4;i++){ x0+=x1; x1=rotl32c(x1,rB[i]); x1^=x0; }
  x0 += k1; x1 += k2 + 4u;
  for (int i=0;i<4;i++){ x0+=x1; x1=rotl32c(x1,rA[i]); x1^=x0; }
  x0 += k2; x1 += k0 + 5u;
  return U2{x0, x1};
}

// ---------------------------------------------------------------------------
// Kernel 0: idx[l][s], computed ONCE. r10's m_kernel recomputed this
// per (bh,l) wave — 32x redundant threefry, ~120 of ~200 VALU ops/wave.
// ---------------------------------------------------------------------------
__global__ __launch_bounds__(256) void idx_kernel(int* __restrict__ idx)
{
  unsigned j = blockIdx.x*256u + threadIdx.x;
  if (j >= 81920u) return;
  constexpr U2 K2 = tf2x32(0u, 42u, 0u, 1u);
  U2 r = tf2x32(K2.a, K2.b, 0u, j);
  idx[j] = (int)((r.a ^ r.b) & 2047u);
}

// ---------------------------------------------------------------------------
// Kernel 1: M[b,h,l] = max_s(q.k_s) - sum_s(q.k_s)/2048 over 40 sampled keys.
// One wave per (bh,l); 8 sample-groups x 8 lanes, coalesced 256 B row reads;
// idx loaded (1 coalesced dword). 512 consecutive blocks per bh -> L2 slab.
// ---------------------------------------------------------------------------
__global__ __launch_bounds__(256) void m_kernel(const float* __restrict__ q,
                                                const float* __restrict__ k,
                                                const int*   __restrict__ idx,
                                                float*       __restrict__ M)
{
  int g    = blockIdx.x;        // 16384
  int bh   = g >> 9;
  int lblk = g & 511;
  int w    = threadIdx.x >> 6, lane = threadIdx.x & 63;
  int l    = lblk*4 + w;
  int b = bh >> 3, h = bh & 7;
  int grp  = lane >> 3;
  int l8   = lane & 7;
  const float* qrow = q + (size_t)(b*L_ + l)*HD + h*D_;
  float4 q0 = *(const float4*)(qrow + l8*8);
  float4 q1 = *(const float4*)(qrow + l8*8 + 4);
  int myidx = (lane < U_) ? idx[l*U_ + lane] : 0;
  const float* kbase = k + (size_t)b*L_*HD + h*D_;
  float vmax = -INFINITY, vsum = 0.f;
  #pragma unroll
  for (int t=0;t<5;t++){
    int s = t*8 + grp;
    int kidx = __shfl(myidx, s, 64);
    const float* krow = kbase + (size_t)kidx*HD;
    float4 k0 = *(const float4*)(krow + l8*8);
    float4 k1 = *(const float4*)(krow + l8*8 + 4);
    float p = q0.x*k0.x + q0.y*k0.y + q0.z*k0.z + q0.w*k0.w
            + q1.x*k1.x + q1.y*k1.y + q1.z*k1.z + q1.w*k1.w;
    p += __shfl_xor(p, 1, 64);
    p += __shfl_xor(p, 2, 64);
    p += __shfl_xor(p, 4, 64);
    vmax = fmaxf(vmax, p);
    vsum += p;
  }
  vmax = fmaxf(vmax, __shfl_xor(vmax, 8, 64));
  vmax = fmaxf(vmax, __shfl_xor(vmax,16, 64));
  vmax = fmaxf(vmax, __shfl_xor(vmax,32, 64));
  vsum += __shfl_xor(vsum, 8, 64);
  vsum += __shfl_xor(vsum,16, 64);
  vsum += __shfl_xor(vsum,32, 64);
  if (lane == 0) M[bh*L_ + l] = vmax - vsum * (1.0f/(float)L_);
}

// ---------------------------------------------------------------------------
// Kernel 2: top-40 per (b,h). Per-thread running (max,idx) in registers;
// only the winner thread rescans its 8 slots each iteration.
// ---------------------------------------------------------------------------
__global__ __launch_bounds__(256) void topk_kernel(const float* __restrict__ M,
                                                   int* __restrict__ mtop)
{
  __shared__ float mv[L_];
  __shared__ float bv[4];
  __shared__ int   bix[4];
  __shared__ int   wsh;
  int bh = blockIdx.x;
  int tid = threadIdx.x, w = tid >> 6, lane = tid & 63;
  float tb = -INFINITY; int ti = tid;
  #pragma unroll
  for (int i=0;i<8;i++){
    float vv = M[bh*L_ + tid + 256*i];
    mv[tid + 256*i] = vv;
    if (vv > tb){ tb = vv; ti = tid + 256*i; }
  }
  for (int it=0; it<U_; ++it){
    float best = tb; int bi = ti;
    #pragma unroll
    for (int off=32; off; off>>=1){
      float ov = __shfl_xor(best, off, 64);
      int   oi = __shfl_xor(bi,   off, 64);
      if (ov > best || (ov == best && oi < bi)){ best = ov; bi = oi; }
    }
    if (lane == 0){ bv[w] = best; bix[w] = bi; }
    __syncthreads();
    if (tid == 0){
      float bb = bv[0]; int ii = bix[0];
      #pragma unroll
      for (int j=1;j<4;j++)
        if (bv[j] > bb || (bv[j] == bb && bix[j] < ii)){ bb = bv[j]; ii = bix[j]; }
      mtop[bh*U_ + it] = ii; wsh = ii;
    }
    __syncthreads();
    int wi = wsh;
    if (ti == wi){
      mv[wi] = -INFINITY;
      tb = -INFINITY; ti = tid;
      #pragma unroll
      for (int i=0;i<8;i++){
        float vv = mv[tid + 256*i];
        if (vv > tb){ tb = vv; ti = tid + 256*i; }
      }
    }
  }
}

// ---------------------------------------------------------------------------
// Kernel 3: V column sums (for mean), atomics into vmean (pre-zeroed;
// only 2048 destinations — not the r9 pathology).
// ---------------------------------------------------------------------------
__global__ __launch_bounds__(256) void vmean_kernel(const float* __restrict__ v,
                                                    float* __restrict__ vmean)
{
  int g = blockIdx.x;
  int bh = g & 31, chunk = g >> 5;
  int b = bh >> 3, h = bh & 7;
  int w = threadIdx.x >> 6, lane = threadIdx.x & 63;
  int l0 = chunk*128 + w*32;
  float s = 0.f;
  for (int i=0;i<32;i++)
    s += v[(size_t)(b*L_ + l0 + i)*HD + h*D_ + lane];
  atomicAdd(&vmean[bh*D_ + lane], s);
}

// ---------------------------------------------------------------------------
// Kernel 4: out[b][l][h][:] = V_mean (sum * 1/2048), float4 stores.
// ---------------------------------------------------------------------------
__global__ __launch_bounds__(256) void init_kernel(const float* __restrict__ vmean,
                                                   float* __restrict__ out)
{
  int i = blockIdx.x*256 + threadIdx.x;
  int d4 = i & 15;
  int h  = (i >> 4) & 7;
  int bl = i >> 7;
  int b  = bl >> 11;
  float4 vm = ((const float4*)(vmean + (b*H_ + h)*D_))[d4];
  const float sc = 1.0f/(float)L_;
  float4 o; o.x = vm.x*sc; o.y = vm.y*sc; o.z = vm.z*sc; o.w = vm.w*sc;
  ((float4*)out)[i] = o;
}

// ---------------------------------------------------------------------------
// Kernel 5: attention partials, stored exclusive slices (no atomics — r9).
// Grid = 32 bh x KC kc x 2 qg. KC=8 (2 blocks/CU; r10 ran 256 blocks =
// 1/CU, 1 wave/SIMD, all LDS latency exposed) when ws permits, else KC=4.
// Block: 4 waves; wave owns 5 queries; nt=16/KC runtime-trip 128-key tiles
// (runtime loop + __launch_bounds__(256,3) = proven anti-spill, VGPR 84).
// Kt pad-68 (0 conflicts), Vt in LDS, psQ overlays Kt after scores.
// p = exp(s/8), no max-shift (validated r7-r10).
// ---------------------------------------------------------------------------
__global__ __launch_bounds__(256, 3) void attn_kernel(const float* __restrict__ q,
                                                      const float* __restrict__ k,
                                                      const float* __restrict__ v,
                                                      const int*   __restrict__ mtop,
                                                      float* __restrict__ pacc,
                                                      float* __restrict__ pl,
                                                      int nt, int KC)
{
  __shared__ float sh[128*68 + 128*64 + 20*64];  // Kt + Vt + Qs = 72,704 B
  float* Kt  = sh;                 // psQ[20][128] overlays after scores
  float* Vt  = sh + 128*68;
  float* Qs  = sh + 128*68 + 128*64;
  float* psQ = sh;

  int g  = blockIdx.x;             // 64*KC
  int bh = g & 31, j = g >> 5;
  int kc = j >> 1, qg = j & 1;
  int b = bh >> 3, h = bh & 7;
  int tid = threadIdx.x, w = tid >> 6, lane = tid & 63;

  // stage Qs: 20 rows x 16 float4 = 320 float4
  #pragma unroll
  for (int c=0;c<2;c++){
    int flat = c*256 + tid;
    if (flat < 320){
      int row = flat >> 4, col = flat & 15;
      int lstar = mtop[bh*U_ + qg*20 + row];
      ((float4*)(Qs + row*64))[col] =
        ((const float4*)(q + (size_t)(b*L_ + lstar)*HD + h*D_))[col];
    }
  }

  float acc[5], lsum[5];
  #pragma unroll
  for (int qq=0;qq<5;qq++){ acc[qq] = 0.f; lsum[qq] = 0.f; }

  for (int tt=0; tt<nt; ++tt){     // runtime trip count pins code shape
    int kt = (kc*nt + tt)*128;
    __syncthreads();               // Qs ready / prior tile's psQ+Vt reads done
    #pragma unroll
    for (int c=0;c<8;c++){
      int flat = c*256 + tid;
      int row = flat >> 4, col = flat & 15;
      ((float4*)(Kt + row*68))[col] =
        ((const float4*)(k + (size_t)(b*L_ + kt + row)*HD + h*D_))[col];
      ((float4*)(Vt + row*64))[col] =
        ((const float4*)(v + (size_t)(b*L_ + kt + row)*HD + h*D_))[col];
    }
    __syncthreads();

    // scores: 5 queries x 2 keys per lane
    float s0[5], s1[5];
    #pragma unroll
    for (int qq=0;qq<5;qq++){ s0[qq] = 0.f; s1[qq] = 0.f; }
    const float* kr0 = Kt + lane*68;
    const float* kr1 = Kt + (lane+64)*68;
    #pragma unroll
    for (int t=0;t<16;t++){
      float4 k0 = ((const float4*)kr0)[t];
      float4 k1 = ((const float4*)kr1)[t];
      #pragma unroll
      for (int qq=0;qq<5;qq++){
        float4 qf = ((const float4*)(Qs + (w*5+qq)*64))[t];
        s0[qq] += k0.x*qf.x + k0.y*qf.y + k0.z*qf.z + k0.w*qf.w;
        s1[qq] += k1.x*qf.x + k1.y*qf.y + k1.z*qf.z + k1.w*qf.w;
      }
    }
    __syncthreads();   // Kt reads done before psQ overlay

    #pragma unroll
    for (int qq=0;qq<5;qq++){
      float p0 = __expf(s0[qq]*0.125f);
      float p1 = __expf(s1[qq]*0.125f);
      psQ[(w*5+qq)*128 + lane]      = p0;
      psQ[(w*5+qq)*128 + lane + 64] = p1;
      lsum[qq] += p0 + p1;         // per-lane; reduced once in epilogue
    }
    __syncthreads();   // psQ visible before PV / next restage

    // PV: lane = output dim; wave's 5 queries, all 128 keys from Vt
    for (int k4=0;k4<32;k4++){
      float v0 = Vt[(4*k4+0)*64 + lane];
      float v1 = Vt[(4*k4+1)*64 + lane];
      float v2 = Vt[(4*k4+2)*64 + lane];
      float v3 = Vt[(4*k4+3)*64 + lane];
      #pragma unroll
      for (int qq=0;qq<5;qq++){
        float4 pp = ((const float4*)(psQ + (w*5+qq)*128))[k4];
        acc[qq] += pp.x*v0 + pp.y*v1 + pp.z*v2 + pp.w*v3;
      }
    }
  }

  // epilogue: exclusive (gu,kc) partial slice — no atomics
  #pragma unroll
  for (int qq=0;qq<5;qq++){
    float ls = lsum[qq];
    #pragma unroll
    for (int off=32; off; off>>=1) ls += __shfl_xor(ls, off, 64);
    int gu = bh*U_ + qg*20 + w*5 + qq;
    pacc[(size_t)(gu*KC + kc)*64 + lane] = acc[qq];
    if (lane == 0) pl[gu*KC + kc] = ls;
  }
}

// ---------------------------------------------------------------------------
// Kernel 6: sum KC partials per (bh,u), normalize, scatter selected rows.
// ---------------------------------------------------------------------------
__global__ __launch_bounds__(256) void combine_kernel(const int* __restrict__ mtop,
                                                      const float* __restrict__ pacc,
                                                      const float* __restrict__ pl,
                                                      float* __restrict__ out,
                                                      int KC)
{
  int gu = blockIdx.x*4 + (threadIdx.x >> 6);  // 0..1279
  int lane = threadIdx.x & 63;
  int bh = gu / U_, u = gu - bh*U_;
  float a = 0.f, L = 0.f;
  for (int c=0;c<KC;c++){
    a += pacc[(size_t)(gu*KC + c)*64 + lane];
    L += pl[gu*KC + c];
  }
  int b = bh >> 3, h = bh & 7;
  int lstar = mtop[bh*U_ + u];
  out[(size_t)(b*L_ + lstar)*HD + h*D_ + lane] = a / L;
}

// ---------------------------------------------------------------------------
extern "C" void kernel_launch(void* const* d_in, const int* in_sizes, int n_in,
                              void* d_out, int out_size, void* d_ws, size_t ws_size,
                              hipStream_t stream)
{
  const float* q = (const float*)d_in[0];
  const float* k = (const float*)d_in[1];
  const float* v = (const float*)d_in[2];
  float* out = (float*)d_out;

  int KC = (ws_size >= (size_t)WS_NEED_KC8) ? 8 : 4;
  int nt = 16 / KC;

  // runtime layout (see header comment)
  size_t o_pl    = (size_t)1280*KC*64*4;
  size_t o_vmean = o_pl + (size_t)1280*KC*4;
  size_t o_M     = o_vmean + 2048*4;
  size_t o_mtop  = o_M + 65536*4;
  size_t o_idx   = o_mtop + 1280*4;

  float* pacc  = (float*)d_ws;
  float* pl    = (float*)((char*)d_ws + o_pl);
  float* vmean = (float*)((char*)d_ws + o_vmean);
  float* M     = (float*)((char*)d_ws + o_M);
  int*   mtop  = (int*)  ((char*)d_ws + o_mtop);
  int*   idx   = (int*)  ((char*)d_ws + o_idx);

  hipMemsetAsync(vmean, 0, 2048*sizeof(float), stream);
  idx_kernel    <<<320,   256, 0, stream>>>(idx);
  m_kernel      <<<16384, 256, 0, stream>>>(q, k, idx, M);
  topk_kernel   <<<32,    256, 0, stream>>>(M, mtop);
  vmean_kernel  <<<512,   256, 0, stream>>>(v, vmean);
  init_kernel   <<<4096,  256, 0, stream>>>(vmean, out);
  attn_kernel   <<<64*KC, 256, 0, stream>>>(q, k, v, mtop, pacc, pl, nt, KC);
  combine_kernel<<<320,   256, 0, stream>>>(mtop, pacc, pl, out, KC);
}

// Round 12
// 195.039 us; speedup vs baseline: 2.0205x; 1.0820x over previous
//
#include <hip/hip_runtime.h>
#include <math.h>

#define B_  4
#define L_  2048
#define H_  8
#define D_  64
#define U_  40
#define HD  (H_*D_)   // 512

// ---------------------------------------------------------------------------
// Workspace (runtime-selected KC):
//  KC=8 needs 2,937,856 B: pacc[1280*8*64]@0, pl[1280*8]@2621440,
//    vmean@2662400, M@2670592, mtop@2932736
//  KC=4 needs 1,606,656 B (r10/r11-proven footprint)
// ---------------------------------------------------------------------------
#define WS_NEED_KC8 2937856

// ---------------------------------------------------------------------------
// threefry2x32 (jax partitionable stream) — verified bit-exact round 4.
// randint(key(42),(2048,40),0,2048) = tf(k2,(0,j)).b1 ^ .b2 & 2047,
// k2 = tf((0,42),(0,1)) constexpr.
// ---------------------------------------------------------------------------
struct U2 { unsigned a, b; };

__host__ __device__ constexpr unsigned rotl32c(unsigned x, int r){
  return (x<<r)|(x>>(32-r));
}

__host__ __device__ constexpr U2 tf2x32(unsigned k0, unsigned k1,
                                        unsigned x0, unsigned x1)
{
  const unsigned k2 = k0 ^ k1 ^ 0x1BD11BDAu;
  const int rA[4] = {13,15,26,6};
  const int rB[4] = {17,29,16,24};
  x0 += k0; x1 += k1;
  for (int i=0;i<4;i++){ x0+=x1; x1=rotl32c(x1,rA[i]); x1^=x0; }
  x0 += k1; x1 += k2 + 1u;
  for (int i=0;i<4;i++){ x0+=x1; x1=rotl32c(x1,rB[i]); x1^=x0; }
  x0 += k2; x1 += k0 + 2u;
  for (int i=0;i<4;i++){ x0+=x1; x1=rotl32c(x1,rA[i]); x1^=x0; }
  x0 += k0; x1 += k1 + 3u;
  for (int i=0;i<4;i++){ x0+=x1; x1=rotl32c(x1,rB[i]); x1^=x0; }
  x0 += k1; x1 += k2 + 4u;
  for (int i=0;i<4;i++){ x0+=x1; x1=rotl32c(x1,rA[i]); x1^=x0; }
  x0 += k2; x1 += k0 + 5u;
  return U2{x0, x1};
}

// ---------------------------------------------------------------------------
// Kernel 1: M[b,h,l] for ALL h in one wave. r11 was traffic-bound (FETCH
// 73.5 MB / 1.4 TB/s == dur): strided 256 B h-slices + all-8-XCDs-on-one-
// slab duplication. Now: wave = one (b,l); lane = h*8+d8 reads the FULL
// 2 KB K row contiguously (2 float4); dot reduced over d8 (xor 1,2,4);
// vmax/vsum accumulate in-register across the 40 samples (no final 40-lane
// reduce). Grid g=lblk*4+b -> b=g&3: each XCD pair owns one b, K[b]=4 MB
// = one XCD L2. Threefry fused (one lane-parallel hash per wave, its own l
// — zero redundancy; idx_kernel dispatch eliminated).
// ---------------------------------------------------------------------------
__global__ __launch_bounds__(256) void m_kernel(const float* __restrict__ q,
                                                const float* __restrict__ k,
                                                float*       __restrict__ M)
{
  int g    = blockIdx.x;          // 2048: g = lblk*4 + b
  int b    = g & 3;
  int lblk = g >> 2;
  int w    = threadIdx.x >> 6, lane = threadIdx.x & 63;
  int l    = lblk*4 + w;
  int h    = lane >> 3, d8 = lane & 7;

  // q row (all h): lane's 8 floats = q[b][l][h*64 + d8*8 ..+8]
  const float* qrow = q + (size_t)(b*L_ + l)*HD;
  float4 q0 = *(const float4*)(qrow + lane*8);
  float4 q1 = *(const float4*)(qrow + lane*8 + 4);

  // idx for this l: lane-parallel threefry (lanes 0..39)
  constexpr U2 K2 = tf2x32(0u, 42u, 0u, 1u);
  int myidx = 0;
  if (lane < U_){
    U2 r = tf2x32(K2.a, K2.b, 0u, (unsigned)(l*U_ + lane));
    myidx = (int)((r.a ^ r.b) & 2047u);
  }

  const float* kb = k + (size_t)b*L_*HD;
  float vmax = -INFINITY, vsum = 0.f;
  #pragma unroll 5
  for (int s=0;s<U_;s++){
    int kidx = __shfl(myidx, s, 64);
    const float* kr = kb + (size_t)kidx*HD;
    float4 k0 = *(const float4*)(kr + lane*8);
    float4 k1 = *(const float4*)(kr + lane*8 + 4);
    float p = q0.x*k0.x + q0.y*k0.y + q0.z*k0.z + q0.w*k0.w
            + q1.x*k1.x + q1.y*k1.y + q1.z*k1.z + q1.w*k1.w;
    p += __shfl_xor(p, 1, 64);
    p += __shfl_xor(p, 2, 64);
    p += __shfl_xor(p, 4, 64);    // all 8 lanes of h now hold dot(s)
    vmax = fmaxf(vmax, p);
    vsum += p;
  }
  if (d8 == 0)
    M[(b*8 + h)*L_ + l] = vmax - vsum * (1.0f/(float)L_);
}

// ---------------------------------------------------------------------------
// Kernel 2: top-40 per (b,h). Per-thread running (max,idx) in registers;
// only the winner thread rescans its 8 slots each iteration.
// ---------------------------------------------------------------------------
__global__ __launch_bounds__(256) void topk_kernel(const float* __restrict__ M,
                                                   int* __restrict__ mtop)
{
  __shared__ float mv[L_];
  __shared__ float bv[4];
  __shared__ int   bix[4];
  __shared__ int   wsh;
  int bh = blockIdx.x;
  int tid = threadIdx.x, w = tid >> 6, lane = tid & 63;
  float tb = -INFINITY; int ti = tid;
  #pragma unroll
  for (int i=0;i<8;i++){
    float vv = M[bh*L_ + tid + 256*i];
    mv[tid + 256*i] = vv;
    if (vv > tb){ tb = vv; ti = tid + 256*i; }
  }
  for (int it=0; it<U_; ++it){
    float best = tb; int bi = ti;
    #pragma unroll
    for (int off=32; off; off>>=1){
      float ov = __shfl_xor(best, off, 64);
      int   oi = __shfl_xor(bi,   off, 64);
      if (ov > best || (ov == best && oi < bi)){ best = ov; bi = oi; }
    }
    if (lane == 0){ bv[w] = best; bix[w] = bi; }
    __syncthreads();
    if (tid == 0){
      float bb = bv[0]; int ii = bix[0];
      #pragma unroll
      for (int j=1;j<4;j++)
        if (bv[j] > bb || (bv[j] == bb && bix[j] < ii)){ bb = bv[j]; ii = bix[j]; }
      mtop[bh*U_ + it] = ii; wsh = ii;
    }
    __syncthreads();
    int wi = wsh;
    if (ti == wi){
      mv[wi] = -INFINITY;
      tb = -INFINITY; ti = tid;
      #pragma unroll
      for (int i=0;i<8;i++){
        float vv = mv[tid + 256*i];
        if (vv > tb){ tb = vv; ti = tid + 256*i; }
      }
    }
  }
}

// ---------------------------------------------------------------------------
// Kernel 3: V column sums (for mean), atomics into vmean (pre-zeroed;
// only 2048 destinations — not the r9 pathology).
// ---------------------------------------------------------------------------
__global__ __launch_bounds__(256) void vmean_kernel(const float* __restrict__ v,
                                                    float* __restrict__ vmean)
{
  int g = blockIdx.x;
  int bh = g & 31, chunk = g >> 5;
  int b = bh >> 3, h = bh & 7;
  int w = threadIdx.x >> 6, lane = threadIdx.x & 63;
  int l0 = chunk*128 + w*32;
  float s = 0.f;
  for (int i=0;i<32;i++)
    s += v[(size_t)(b*L_ + l0 + i)*HD + h*D_ + lane];
  atomicAdd(&vmean[bh*D_ + lane], s);
}

// ---------------------------------------------------------------------------
// Kernel 4: out[b][l][h][:] = V_mean (sum * 1/2048), float4 stores.
// ---------------------------------------------------------------------------
__global__ __launch_bounds__(256) void init_kernel(const float* __restrict__ vmean,
                                                   float* __restrict__ out)
{
  int i = blockIdx.x*256 + threadIdx.x;
  int d4 = i & 15;
  int h  = (i >> 4) & 7;
  int bl = i >> 7;
  int b  = bl >> 11;
  float4 vm = ((const float4*)(vmean + (b*H_ + h)*D_))[d4];
  const float sc = 1.0f/(float)L_;
  float4 o; o.x = vm.x*sc; o.y = vm.y*sc; o.z = vm.z*sc; o.w = vm.w*sc;
  ((float4*)out)[i] = o;
}

// ---------------------------------------------------------------------------
// Kernel 5: attention partials, stored exclusive slices (no atomics — r9).
// Grid = 32 bh x KC kc x 2 qg; KC=8 when ws permits (2 blocks/CU), else 4.
// Block: 4 waves; wave owns 5 queries; nt=16/KC runtime-trip 128-key tiles
// (runtime loop + __launch_bounds__(256,3) = proven anti-spill, VGPR 84).
// Kt pad-68 (0 conflicts), Vt in LDS, psQ overlays Kt after scores.
// p = exp(s/8), no max-shift (validated r7-r11).
// ---------------------------------------------------------------------------
__global__ __launch_bounds__(256, 3) void attn_kernel(const float* __restrict__ q,
                                                      const float* __restrict__ k,
                                                      const float* __restrict__ v,
                                                      const int*   __restrict__ mtop,
                                                      float* __restrict__ pacc,
                                                      float* __restrict__ pl,
                                                      int nt, int KC)
{
  __shared__ float sh[128*68 + 128*64 + 20*64];  // Kt + Vt + Qs = 72,704 B
  float* Kt  = sh;                 // psQ[20][128] overlays after scores
  float* Vt  = sh + 128*68;
  float* Qs  = sh + 128*68 + 128*64;
  float* psQ = sh;

  int g  = blockIdx.x;             // 64*KC
  int bh = g & 31, j = g >> 5;
  int kc = j >> 1, qg = j & 1;
  int b = bh >> 3, h = bh & 7;
  int tid = threadIdx.x, w = tid >> 6, lane = tid & 63;

  // stage Qs: 20 rows x 16 float4 = 320 float4
  #pragma unroll
  for (int c=0;c<2;c++){
    int flat = c*256 + tid;
    if (flat < 320){
      int row = flat >> 4, col = flat & 15;
      int lstar = mtop[bh*U_ + qg*20 + row];
      ((float4*)(Qs + row*64))[col] =
        ((const float4*)(q + (size_t)(b*L_ + lstar)*HD + h*D_))[col];
    }
  }

  float acc[5], lsum[5];
  #pragma unroll
  for (int qq=0;qq<5;qq++){ acc[qq] = 0.f; lsum[qq] = 0.f; }

  for (int tt=0; tt<nt; ++tt){     // runtime trip count pins code shape
    int kt = (kc*nt + tt)*128;
    __syncthreads();               // Qs ready / prior tile's psQ+Vt reads done
    #pragma unroll
    for (int c=0;c<8;c++){
      int flat = c*256 + tid;
      int row = flat >> 4, col = flat & 15;
      ((float4*)(Kt + row*68))[col] =
        ((const float4*)(k + (size_t)(b*L_ + kt + row)*HD + h*D_))[col];
      ((float4*)(Vt + row*64))[col] =
        ((const float4*)(v + (size_t)(b*L_ + kt + row)*HD + h*D_))[col];
    }
    __syncthreads();

    // scores: 5 queries x 2 keys per lane
    float s0[5], s1[5];
    #pragma unroll
    for (int qq=0;qq<5;qq++){ s0[qq] = 0.f; s1[qq] = 0.f; }
    const float* kr0 = Kt + lane*68;
    const float* kr1 = Kt + (lane+64)*68;
    #pragma unroll
    for (int t=0;t<16;t++){
      float4 k0 = ((const float4*)kr0)[t];
      float4 k1 = ((const float4*)kr1)[t];
      #pragma unroll
      for (int qq=0;qq<5;qq++){
        float4 qf = ((const float4*)(Qs + (w*5+qq)*64))[t];
        s0[qq] += k0.x*qf.x + k0.y*qf.y + k0.z*qf.z + k0.w*qf.w;
        s1[qq] += k1.x*qf.x + k1.y*qf.y + k1.z*qf.z + k1.w*qf.w;
      }
    }
    __syncthreads();   // Kt reads done before psQ overlay

    #pragma unroll
    for (int qq=0;qq<5;qq++){
      float p0 = __expf(s0[qq]*0.125f);
      float p1 = __expf(s1[qq]*0.125f);
      psQ[(w*5+qq)*128 + lane]      = p0;
      psQ[(w*5+qq)*128 + lane + 64] = p1;
      lsum[qq] += p0 + p1;         // per-lane; reduced once in epilogue
    }
    __syncthreads();   // psQ visible before PV / next restage

    // PV: lane = output dim; wave's 5 queries, all 128 keys from Vt
    for (int k4=0;k4<32;k4++){
      float v0 = Vt[(4*k4+0)*64 + lane];
      float v1 = Vt[(4*k4+1)*64 + lane];
      float v2 = Vt[(4*k4+2)*64 + lane];
      float v3 = Vt[(4*k4+3)*64 + lane];
      #pragma unroll
      for (int qq=0;qq<5;qq++){
        float4 pp = ((const float4*)(psQ + (w*5+qq)*128))[k4];
        acc[qq] += pp.x*v0 + pp.y*v1 + pp.z*v2 + pp.w*v3;
      }
    }
  }

  // epilogue: exclusive (gu,kc) partial slice — no atomics
  #pragma unroll
  for (int qq=0;qq<5;qq++){
    float ls = lsum[qq];
    #pragma unroll
    for (int off=32; off; off>>=1) ls += __shfl_xor(ls, off, 64);
    int gu = bh*U_ + qg*20 + w*5 + qq;
    pacc[(size_t)(gu*KC + kc)*64 + lane] = acc[qq];
    if (lane == 0) pl[gu*KC + kc] = ls;
  }
}

// ---------------------------------------------------------------------------
// Kernel 6: sum KC partials per (bh,u), normalize, scatter selected rows.
// ---------------------------------------------------------------------------
__global__ __launch_bounds__(256) void combine_kernel(const int* __restrict__ mtop,
                                                      const float* __restrict__ pacc,
                                                      const float* __restrict__ pl,
                                                      float* __restrict__ out,
                                                      int KC)
{
  int gu = blockIdx.x*4 + (threadIdx.x >> 6);  // 0..1279
  int lane = threadIdx.x & 63;
  int bh = gu / U_, u = gu - bh*U_;
  float a = 0.f, L = 0.f;
  for (int c=0;c<KC;c++){
    a += pacc[(size_t)(gu*KC + c)*64 + lane];
    L += pl[gu*KC + c];
  }
  int b = bh >> 3, h = bh & 7;
  int lstar = mtop[bh*U_ + u];
  out[(size_t)(b*L_ + lstar)*HD + h*D_ + lane] = a / L;
}

// ---------------------------------------------------------------------------
extern "C" void kernel_launch(void* const* d_in, const int* in_sizes, int n_in,
                              void* d_out, int out_size, void* d_ws, size_t ws_size,
                              hipStream_t stream)
{
  const float* q = (const float*)d_in[0];
  const float* k = (const float*)d_in[1];
  const float* v = (const float*)d_in[2];
  float* out = (float*)d_out;

  int KC = (ws_size >= (size_t)WS_NEED_KC8) ? 8 : 4;
  int nt = 16 / KC;

  size_t o_pl    = (size_t)1280*KC*64*4;
  size_t o_vmean = o_pl + (size_t)1280*KC*4;
  size_t o_M     = o_vmean + 2048*4;
  size_t o_mtop  = o_M + 65536*4;

  float* pacc  = (float*)d_ws;
  float* pl    = (float*)((char*)d_ws + o_pl);
  float* vmean = (float*)((char*)d_ws + o_vmean);
  float* M     = (float*)((char*)d_ws + o_M);
  int*   mtop  = (int*)  ((char*)d_ws + o_mtop);

  hipMemsetAsync(vmean, 0, 2048*sizeof(float), stream);
  m_kernel      <<<2048,  256, 0, stream>>>(q, k, M);
  topk_kernel   <<<32,    256, 0, stream>>>(M, mtop);
  vmean_kernel  <<<512,   256, 0, stream>>>(v, vmean);
  init_kernel   <<<4096,  256, 0, stream>>>(vmean, out);
  attn_kernel   <<<64*KC, 256, 0, stream>>>(q, k, v, mtop, pacc, pl, nt, KC);
  combine_kernel<<<320,   256, 0, stream>>>(mtop, pacc, pl, out, KC);
}

// Round 13
// 190.528 us; speedup vs baseline: 2.0684x; 1.0237x over previous
//
#include <hip/hip_runtime.h>
#include <math.h>

#define B_  4
#define L_  2048
#define H_  8
#define D_  64
#define U_  40
#define HD  (H_*D_)   // 512

// ---------------------------------------------------------------------------
// Workspace (ws_size confirmed 256 MiB in r12 — KC=8 layout always fits):
//   pacc[1280*8*64]@0, pl[1280*8]@2621440, vmean@2662400, M@2670592,
//   mtop@2932736 -> 2,937,856 B
// ---------------------------------------------------------------------------
#define WS_NEED_KC8 2937856

// ---------------------------------------------------------------------------
// threefry2x32 (jax partitionable stream) — verified bit-exact round 4.
// randint(key(42),(2048,40),0,2048) = tf(k2,(0,j)).b1 ^ .b2 & 2047,
// k2 = tf((0,42),(0,1)) constexpr.
// ---------------------------------------------------------------------------
struct U2 { unsigned a, b; };

__host__ __device__ constexpr unsigned rotl32c(unsigned x, int r){
  return (x<<r)|(x>>(32-r));
}

__host__ __device__ constexpr U2 tf2x32(unsigned k0, unsigned k1,
                                        unsigned x0, unsigned x1)
{
  const unsigned k2 = k0 ^ k1 ^ 0x1BD11BDAu;
  const int rA[4] = {13,15,26,6};
  const int rB[4] = {17,29,16,24};
  x0 += k0; x1 += k1;
  for (int i=0;i<4;i++){ x0+=x1; x1=rotl32c(x1,rA[i]); x1^=x0; }
  x0 += k1; x1 += k2 + 1u;
  for (int i=0;i<4;i++){ x0+=x1; x1=rotl32c(x1,rB[i]); x1^=x0; }
  x0 += k2; x1 += k0 + 2u;
  for (int i=0;i<4;i++){ x0+=x1; x1=rotl32c(x1,rA[i]); x1^=x0; }
  x0 += k0; x1 += k1 + 3u;
  for (int i=0;i<4;i++){ x0+=x1; x1=rotl32c(x1,rB[i]); x1^=x0; }
  x0 += k1; x1 += k2 + 4u;
  for (int i=0;i<4;i++){ x0+=x1; x1=rotl32c(x1,rA[i]); x1^=x0; }
  x0 += k2; x1 += k0 + 5u;
  return U2{x0, x1};
}

// ---------------------------------------------------------------------------
// Dispatch 2 kernel: vmean(512 blocks) || M-scores(2048 blocks), fused.
// Independent work co-scheduled: vmean's V streaming hides in m's L2-gather
// stalls; saves a serialized dispatch. vmean blocks first (finish early).
// m part: wave = one (b,l), all 8 h; lane = h*8+d8 reads full 2 KB K rows
// contiguously; dot reduced over d8 (xor 1,2,4); vmax/vsum in-register
// across 40 samples; b = g&3 -> each XCD pair owns one 4 MB K[b] slab
// (r12-verified: m_kernel dropped 54 -> <42 us with this shape).
// ---------------------------------------------------------------------------
__global__ __launch_bounds__(256) void mvm_kernel(const float* __restrict__ q,
                                                  const float* __restrict__ k,
                                                  const float* __restrict__ v,
                                                  float* __restrict__ M,
                                                  float* __restrict__ vmean)
{
  int tid = threadIdx.x;
  int w = tid >> 6, lane = tid & 63;

  if (blockIdx.x < 512){
    // ---- vmean part: V column sums, atomics into pre-zeroed vmean ----
    int g = blockIdx.x;
    int bh = g & 31, chunk = g >> 5;
    int b = bh >> 3, h = bh & 7;
    int l0 = chunk*128 + w*32;
    float s = 0.f;
    for (int i=0;i<32;i++)
      s += v[(size_t)(b*L_ + l0 + i)*HD + h*D_ + lane];
    atomicAdd(&vmean[bh*D_ + lane], s);
    return;
  }

  // ---- M part ----
  int g    = blockIdx.x - 512;    // 0..2047, g = lblk*4 + b
  int b    = g & 3;
  int lblk = g >> 2;
  int l    = lblk*4 + w;
  int h    = lane >> 3, d8 = lane & 7;

  const float* qrow = q + (size_t)(b*L_ + l)*HD;
  float4 q0 = *(const float4*)(qrow + lane*8);
  float4 q1 = *(const float4*)(qrow + lane*8 + 4);

  constexpr U2 K2 = tf2x32(0u, 42u, 0u, 1u);
  int myidx = 0;
  if (lane < U_){
    U2 r = tf2x32(K2.a, K2.b, 0u, (unsigned)(l*U_ + lane));
    myidx = (int)((r.a ^ r.b) & 2047u);
  }

  const float* kb = k + (size_t)b*L_*HD;
  float vmax = -INFINITY, vsum = 0.f;
  #pragma unroll 8
  for (int s=0;s<U_;s++){
    int kidx = __shfl(myidx, s, 64);
    const float* kr = kb + (size_t)kidx*HD;
    float4 k0 = *(const float4*)(kr + lane*8);
    float4 k1 = *(const float4*)(kr + lane*8 + 4);
    float p = q0.x*k0.x + q0.y*k0.y + q0.z*k0.z + q0.w*k0.w
            + q1.x*k1.x + q1.y*k1.y + q1.z*k1.z + q1.w*k1.w;
    p += __shfl_xor(p, 1, 64);
    p += __shfl_xor(p, 2, 64);
    p += __shfl_xor(p, 4, 64);    // all 8 lanes of h now hold dot(s)
    vmax = fmaxf(vmax, p);
    vsum += p;
  }
  if (d8 == 0)
    M[(b*8 + h)*L_ + l] = vmax - vsum * (1.0f/(float)L_);
}

// ---------------------------------------------------------------------------
// Dispatch 3 kernel: topk(32 blocks) || init(4096 blocks), fused.
// topk used 32/256 CUs with 224 idle (latency-bound 40x argmax loop);
// init's 16 MB streaming write now fills them. topk blocks first.
// ---------------------------------------------------------------------------
__global__ __launch_bounds__(256) void topk_init_kernel(const float* __restrict__ M,
                                                        const float* __restrict__ vmean,
                                                        int*   __restrict__ mtop,
                                                        float* __restrict__ out)
{
  int tid = threadIdx.x;

  if (blockIdx.x >= 32){
    // ---- init part: out[b][l][h][:] = vmean_sum * 1/2048 ----
    int i = (blockIdx.x - 32)*256 + tid;    // float4 index, 0..1048575
    int d4 = i & 15;
    int h  = (i >> 4) & 7;
    int bl = i >> 7;
    int b  = bl >> 11;
    float4 vm = ((const float4*)(vmean + (b*H_ + h)*D_))[d4];
    const float sc = 1.0f/(float)L_;
    float4 o; o.x = vm.x*sc; o.y = vm.y*sc; o.z = vm.z*sc; o.w = vm.w*sc;
    ((float4*)out)[i] = o;
    return;
  }

  // ---- topk part: per-thread running (max,idx) in registers; only the
  // winner thread rescans its 8 slots each iteration (r8-proven). ----
  __shared__ float mv[L_];
  __shared__ float bv[4];
  __shared__ int   bix[4];
  __shared__ int   wsh;
  int bh = blockIdx.x;
  int w = tid >> 6, lane = tid & 63;
  float tb = -INFINITY; int ti = tid;
  #pragma unroll
  for (int i=0;i<8;i++){
    float vv = M[bh*L_ + tid + 256*i];
    mv[tid + 256*i] = vv;
    if (vv > tb){ tb = vv; ti = tid + 256*i; }
  }
  for (int it=0; it<U_; ++it){
    float best = tb; int bi = ti;
    #pragma unroll
    for (int off=32; off; off>>=1){
      float ov = __shfl_xor(best, off, 64);
      int   oi = __shfl_xor(bi,   off, 64);
      if (ov > best || (ov == best && oi < bi)){ best = ov; bi = oi; }
    }
    if (lane == 0){ bv[w] = best; bix[w] = bi; }
    __syncthreads();
    if (tid == 0){
      float bb = bv[0]; int ii = bix[0];
      #pragma unroll
      for (int j=1;j<4;j++)
        if (bv[j] > bb || (bv[j] == bb && bix[j] < ii)){ bb = bv[j]; ii = bix[j]; }
      mtop[bh*U_ + it] = ii; wsh = ii;
    }
    __syncthreads();
    int wi = wsh;
    if (ti == wi){
      mv[wi] = -INFINITY;
      tb = -INFINITY; ti = tid;
      #pragma unroll
      for (int i=0;i<8;i++){
        float vv = mv[tid + 256*i];
        if (vv > tb){ tb = vv; ti = tid + 256*i; }
      }
    }
  }
}

// ---------------------------------------------------------------------------
// Kernel: attention partials, stored exclusive slices (no atomics — r9).
// Grid = 32 bh x KC kc x 2 qg; KC=8 (512 blocks = 2/CU, LDS-capped).
// Block: 4 waves; wave owns 5 queries; nt=16/KC runtime-trip 128-key tiles
// (runtime loop + __launch_bounds__(256,3) = proven anti-spill, VGPR 84).
// Kt pad-68 (0 conflicts), Vt in LDS, psQ overlays Kt after scores.
// p = exp(s/8), no max-shift (validated r7-r12). bh = g&31 -> all 16
// blocks of a bh on XCD bh%8: per-XCD K+V working set = 4 MB = L2.
// ---------------------------------------------------------------------------
__global__ __launch_bounds__(256, 3) void attn_kernel(const float* __restrict__ q,
                                                      const float* __restrict__ k,
                                                      const float* __restrict__ v,
                                                      const int*   __restrict__ mtop,
                                                      float* __restrict__ pacc,
                                                      float* __restrict__ pl,
                                                      int nt, int KC)
{
  __shared__ float sh[128*68 + 128*64 + 20*64];  // Kt + Vt + Qs = 72,704 B
  float* Kt  = sh;                 // psQ[20][128] overlays after scores
  float* Vt  = sh + 128*68;
  float* Qs  = sh + 128*68 + 128*64;
  float* psQ = sh;

  int g  = blockIdx.x;             // 64*KC
  int bh = g & 31, j = g >> 5;
  int kc = j >> 1, qg = j & 1;
  int b = bh >> 3, h = bh & 7;
  int tid = threadIdx.x, w = tid >> 6, lane = tid & 63;

  // stage Qs: 20 rows x 16 float4 = 320 float4
  #pragma unroll
  for (int c=0;c<2;c++){
    int flat = c*256 + tid;
    if (flat < 320){
      int row = flat >> 4, col = flat & 15;
      int lstar = mtop[bh*U_ + qg*20 + row];
      ((float4*)(Qs + row*64))[col] =
        ((const float4*)(q + (size_t)(b*L_ + lstar)*HD + h*D_))[col];
    }
  }

  float acc[5], lsum[5];
  #pragma unroll
  for (int qq=0;qq<5;qq++){ acc[qq] = 0.f; lsum[qq] = 0.f; }

  for (int tt=0; tt<nt; ++tt){     // runtime trip count pins code shape
    int kt = (kc*nt + tt)*128;
    __syncthreads();               // Qs ready / prior tile's psQ+Vt reads done
    #pragma unroll
    for (int c=0;c<8;c++){
      int flat = c*256 + tid;
      int row = flat >> 4, col = flat & 15;
      ((float4*)(Kt + row*68))[col] =
        ((const float4*)(k + (size_t)(b*L_ + kt + row)*HD + h*D_))[col];
      ((float4*)(Vt + row*64))[col] =
        ((const float4*)(v + (size_t)(b*L_ + kt + row)*HD + h*D_))[col];
    }
    __syncthreads();

    // scores: 5 queries x 2 keys per lane
    float s0[5], s1[5];
    #pragma unroll
    for (int qq=0;qq<5;qq++){ s0[qq] = 0.f; s1[qq] = 0.f; }
    const float* kr0 = Kt + lane*68;
    const float* kr1 = Kt + (lane+64)*68;
    #pragma unroll
    for (int t=0;t<16;t++){
      float4 k0 = ((const float4*)kr0)[t];
      float4 k1 = ((const float4*)kr1)[t];
      #pragma unroll
      for (int qq=0;qq<5;qq++){
        float4 qf = ((const float4*)(Qs + (w*5+qq)*64))[t];
        s0[qq] += k0.x*qf.x + k0.y*qf.y + k0.z*qf.z + k0.w*qf.w;
        s1[qq] += k1.x*qf.x + k1.y*qf.y + k1.z*qf.z + k1.w*qf.w;
      }
    }
    __syncthreads();   // Kt reads done before psQ overlay

    #pragma unroll
    for (int qq=0;qq<5;qq++){
      float p0 = __expf(s0[qq]*0.125f);
      float p1 = __expf(s1[qq]*0.125f);
      psQ[(w*5+qq)*128 + lane]      = p0;
      psQ[(w*5+qq)*128 + lane + 64] = p1;
      lsum[qq] += p0 + p1;         // per-lane; reduced once in epilogue
    }
    __syncthreads();   // psQ visible before PV / next restage

    // PV: lane = output dim; wave's 5 queries, all 128 keys from Vt
    for (int k4=0;k4<32;k4++){
      float v0 = Vt[(4*k4+0)*64 + lane];
      float v1 = Vt[(4*k4+1)*64 + lane];
      float v2 = Vt[(4*k4+2)*64 + lane];
      float v3 = Vt[(4*k4+3)*64 + lane];
      #pragma unroll
      for (int qq=0;qq<5;qq++){
        float4 pp = ((const float4*)(psQ + (w*5+qq)*128))[k4];
        acc[qq] += pp.x*v0 + pp.y*v1 + pp.z*v2 + pp.w*v3;
      }
    }
  }

  // epilogue: exclusive (gu,kc) partial slice — no atomics
  #pragma unroll
  for (int qq=0;qq<5;qq++){
    float ls = lsum[qq];
    #pragma unroll
    for (int off=32; off; off>>=1) ls += __shfl_xor(ls, off, 64);
    int gu = bh*U_ + qg*20 + w*5 + qq;
    pacc[(size_t)(gu*KC + kc)*64 + lane] = acc[qq];
    if (lane == 0) pl[gu*KC + kc] = ls;
  }
}

// ---------------------------------------------------------------------------
// Kernel: sum KC partials per (bh,u), normalize, scatter selected rows.
// ---------------------------------------------------------------------------
__global__ __launch_bounds__(256) void combine_kernel(const int* __restrict__ mtop,
                                                      const float* __restrict__ pacc,
                                                      const float* __restrict__ pl,
                                                      float* __restrict__ out,
                                                      int KC)
{
  int gu = blockIdx.x*4 + (threadIdx.x >> 6);  // 0..1279
  int lane = threadIdx.x & 63;
  int bh = gu / U_, u = gu - bh*U_;
  float a = 0.f, L = 0.f;
  for (int c=0;c<KC;c++){
    a += pacc[(size_t)(gu*KC + c)*64 + lane];
    L += pl[gu*KC + c];
  }
  int b = bh >> 3, h = bh & 7;
  int lstar = mtop[bh*U_ + u];
  out[(size_t)(b*L_ + lstar)*HD + h*D_ + lane] = a / L;
}

// ---------------------------------------------------------------------------
extern "C" void kernel_launch(void* const* d_in, const int* in_sizes, int n_in,
                              void* d_out, int out_size, void* d_ws, size_t ws_size,
                              hipStream_t stream)
{
  const float* q = (const float*)d_in[0];
  const float* k = (const float*)d_in[1];
  const float* v = (const float*)d_in[2];
  float* out = (float*)d_out;

  int KC = (ws_size >= (size_t)WS_NEED_KC8) ? 8 : 4;
  int nt = 16 / KC;

  size_t o_pl    = (size_t)1280*KC*64*4;
  size_t o_vmean = o_pl + (size_t)1280*KC*4;
  size_t o_M     = o_vmean + 2048*4;
  size_t o_mtop  = o_M + 65536*4;

  float* pacc  = (float*)d_ws;
  float* pl    = (float*)((char*)d_ws + o_pl);
  float* vmean = (float*)((char*)d_ws + o_vmean);
  float* M     = (float*)((char*)d_ws + o_M);
  int*   mtop  = (int*)  ((char*)d_ws + o_mtop);

  hipMemsetAsync(vmean, 0, 2048*sizeof(float), stream);
  mvm_kernel      <<<2560,  256, 0, stream>>>(q, k, v, M, vmean);
  topk_init_kernel<<<4128,  256, 0, stream>>>(M, vmean, mtop, out);
  attn_kernel     <<<64*KC, 256, 0, stream>>>(q, k, v, mtop, pacc, pl, nt, KC);
  combine_kernel  <<<320,   256, 0, stream>>>(mtop, pacc, pl, out, KC);
}